// Round 2
// baseline (154.616 us; speedup 1.0000x reference)
//
#include <hip/hip_runtime.h>

typedef _Float16 half8 __attribute__((ext_vector_type(8)));
typedef _Float16 half4 __attribute__((ext_vector_type(4)));
typedef __fp16 fp16x2 __attribute__((ext_vector_type(2)));
typedef float f32x4 __attribute__((ext_vector_type(4)));

__device__ __forceinline__ void glds16(const void* g, void* l) {
    __builtin_amdgcn_global_load_lds(
        (const __attribute__((address_space(1))) unsigned int*)g,
        (__attribute__((address_space(3))) unsigned int*)l, 16, 0, 0);
}

// ---------------------------------------------------------------------------
// Sizes: B=8, C=512, H=8, D=64, N=1024. Projection: M=1536 (q|k|v), K=512 fp16.
// ---------------------------------------------------------------------------

// Merged prep: [0,384) pack W->fp16; [384,1408) transpose x->fp16; [1408,1664) rel.
__global__ void k_prep_all(const float* __restrict__ Wq, const float* __restrict__ Wk,
                           const float* __restrict__ Wv, const float* __restrict__ bq,
                           const float* __restrict__ bk, const float* __restrict__ bv,
                           const float* __restrict__ x, const float* __restrict__ rel_h,
                           const float* __restrict__ rel_w, _Float16* __restrict__ Wf,
                           float* __restrict__ bias2, _Float16* __restrict__ xTf,
                           _Float16* __restrict__ rel2) {
    __shared__ float xs[64][65];
    int bid = blockIdx.x;
    if (bid < 384) {
        int t = bid * 256 + threadIdx.x;          // 98304 threads
        int m = t >> 6;
        int c8 = (t & 63) << 3;
        const float* src = (m < 512) ? (Wq + m * 512)
                         : (m < 1024 ? (Wk + (m - 512) * 512) : (Wv + (m - 1024) * 512));
        float4 v0 = *(const float4*)(src + c8);
        float4 v1 = *(const float4*)(src + c8 + 4);
        half8 o;
        o[0] = (_Float16)v0.x; o[1] = (_Float16)v0.y; o[2] = (_Float16)v0.z; o[3] = (_Float16)v0.w;
        o[4] = (_Float16)v1.x; o[5] = (_Float16)v1.y; o[6] = (_Float16)v1.z; o[7] = (_Float16)v1.w;
        *(half8*)(Wf + (size_t)m * 512 + c8) = o;
        if (t < 1536)
            bias2[t] = (t < 512) ? bq[t] : (t < 1024 ? bk[t - 512] : bv[t - 1024]);
    } else if (bid < 1408) {
        int i = bid - 384;
        int nt = (i & 15) << 6, ct = ((i >> 4) & 7) << 6, b = i >> 7;
        int t = threadIdx.x;
        const float* xb = x + ((size_t)b * 512 + ct) * 1024 + nt;
#pragma unroll
        for (int p = 0; p < 4; ++p) {
            int c = p * 16 + (t >> 4), n4 = (t & 15) * 4;
            float4 v = *(const float4*)(xb + (size_t)c * 1024 + n4);
            xs[c][n4] = v.x; xs[c][n4 + 1] = v.y; xs[c][n4 + 2] = v.z; xs[c][n4 + 3] = v.w;
        }
        __syncthreads();
        int nl = t >> 2, part = t & 3;
        _Float16* rowp = xTf + ((size_t)b * 1024 + nt + nl) * 512;
#pragma unroll
        for (int g = 0; g < 2; ++g) {
            half8 o;
#pragma unroll
            for (int j = 0; j < 8; ++j)
                o[j] = (_Float16)xs[part * 16 + g * 8 + j][nl];
            *(half8*)(rowp + ct + part * 16 + g * 8) = o;
        }
    } else {
        int tid = (bid - 1408) * 256 + threadIdx.x;   // 65536
        int h = tid >> 13;
        int rem = tid & 8191;
        int n = rem >> 3;
        int g = rem & 7;
        int hh = n & 31, ww = n >> 5;
        half8 o;
#pragma unroll
        for (int j = 0; j < 8; ++j) {
            int d = g * 8 + j;
            o[j] = (_Float16)(rel_h[(h * 64 + d) * 32 + hh] + rel_w[(h * 64 + d) * 32 + ww]);
        }
        *(half8*)(rel2 + ((size_t)h * 1024 + n) * 64 + g * 8) = o;
    }
}

// fp16 GEMM K=512, BK=64; glds16 + XOR-swizzled LDS. Epilogue writes q2 (scaled
// by log2e for the exp2 softmax), k2 ([bh][n][d]) and vb ([bh][d][n]).
__global__ __launch_bounds__(256, 3) void k_proj(const _Float16* __restrict__ Wf,
                                                 const _Float16* __restrict__ xTf,
                                                 const float* __restrict__ bias2,
                                                 _Float16* __restrict__ q2,
                                                 _Float16* __restrict__ k2,
                                                 _Float16* __restrict__ vb) {
    __shared__ __align__(16) _Float16 As[8192];   // [2 kh][128 rows][32 halfs], swizzled
    __shared__ __align__(16) _Float16 Bs[8192];
    int t = threadIdx.x;
    int lane = t & 63, w = t >> 6;
    int lm = lane & 15, lq = lane >> 4;
    int wr = (w >> 1) * 64, wc = (w & 1) * 64;
    int mb = blockIdx.y * 128, nb = blockIdx.x * 128, b = blockIdx.z;
    int rl = lane >> 2;                                   // row within 16-row group
    int csw = ((lane & 3) ^ ((lane >> 3) & 3)) * 8;       // swizzled col (halfs)
    const _Float16* Ag0 = Wf + (size_t)(mb + w * 32 + rl) * 512 + csw;
    const _Float16* Ag1 = Ag0 + 16 * 512;
    const _Float16* Bg0 = xTf + ((size_t)b * 1024 + nb + w * 32 + rl) * 512 + csw;
    const _Float16* Bg1 = Bg0 + 16 * 512;
    f32x4 acc[4][4];
#pragma unroll
    for (int i = 0; i < 4; ++i)
#pragma unroll
        for (int j = 0; j < 4; ++j) acc[i][j] = {0.f, 0.f, 0.f, 0.f};
    int fsw = (lq ^ ((lm >> 1) & 3)) * 8;                 // fragment-read swizzle
    for (int k0 = 0; k0 < 512; k0 += 64) {
#pragma unroll
        for (int kh = 0; kh < 2; ++kh) {
            int ko = k0 + kh * 32;
            glds16(Ag0 + ko, &As[kh * 4096 + (w * 32) * 32]);
            glds16(Ag1 + ko, &As[kh * 4096 + (w * 32 + 16) * 32]);
            glds16(Bg0 + ko, &Bs[kh * 4096 + (w * 32) * 32]);
            glds16(Bg1 + ko, &Bs[kh * 4096 + (w * 32 + 16) * 32]);
        }
        __syncthreads();
#pragma unroll
        for (int kh = 0; kh < 2; ++kh) {
            half8 af[4], bfr[4];
#pragma unroll
            for (int mt = 0; mt < 4; ++mt)
                af[mt] = *(half8*)&As[kh * 4096 + (wr + mt * 16 + lm) * 32 + fsw];
#pragma unroll
            for (int nt = 0; nt < 4; ++nt)
                bfr[nt] = *(half8*)&Bs[kh * 4096 + (wc + nt * 16 + lm) * 32 + fsw];
#pragma unroll
            for (int mt = 0; mt < 4; ++mt)
#pragma unroll
                for (int nt = 0; nt < 4; ++nt)
                    acc[mt][nt] = __builtin_amdgcn_mfma_f32_16x16x32_f16(af[mt], bfr[nt], acc[mt][nt], 0, 0, 0);
        }
        __syncthreads();
    }
    // Epilogue: section 0=q, 1=k, 2=v; head-aligned since (mb+wr)%64==0.
    // q scaled by log2e so k_attn can use native exp2 (S gets the factor exactly:
    // q is the A-half of q·k and the B-half of rel·q).
    int sect = mb >> 9;
    int hloc = ((mb & 511) + wr) >> 6;
    size_t bh = (size_t)b * 8 + hloc;
    if (sect < 2) {
        float sc = (sect == 0) ? 1.44269504089f : 1.0f;
        _Float16* dst = (sect == 0 ? q2 : k2) + bh * 1024 * 64;
#pragma unroll
        for (int mt = 0; mt < 4; ++mt) {
            int d0 = mt * 16 + lq * 4;
            float bi0 = bias2[mb + wr + d0];
            float bi1 = bias2[mb + wr + d0 + 1];
            float bi2 = bias2[mb + wr + d0 + 2];
            float bi3 = bias2[mb + wr + d0 + 3];
#pragma unroll
            for (int nt = 0; nt < 4; ++nt) {
                int n = nb + wc + nt * 16 + lm;
                half4 o;
                o[0] = (_Float16)((acc[mt][nt][0] + bi0) * sc);
                o[1] = (_Float16)((acc[mt][nt][1] + bi1) * sc);
                o[2] = (_Float16)((acc[mt][nt][2] + bi2) * sc);
                o[3] = (_Float16)((acc[mt][nt][3] + bi3) * sc);
                *(half4*)(dst + (size_t)n * 64 + d0) = o;
            }
        }
    } else {
        _Float16* dst = vb + bh * 64 * 1024;
#pragma unroll
        for (int mt = 0; mt < 4; ++mt)
#pragma unroll
            for (int reg = 0; reg < 4; ++reg) {
                int d = mt * 16 + lq * 4 + reg;
                float bi = bias2[mb + wr + d];
#pragma unroll
                for (int nt = 0; nt < 4; ++nt) {
                    int n = nb + wc + nt * 16 + lm;
                    dst[(size_t)d * 1024 + n] = (_Float16)(acc[mt][nt][reg] + bi);
                }
            }
    }
}

// Flash attention, fp16, S^T orientation, Mtile=64 (one q-tile per block;
// grid 1024 -> 4 blocks/CU, occupancy was grid-limited at 512). Named-scalar
// K/V prefetch. exp2 softmax (q pre-scaled), defer-max (THR=8, wave-uniform),
// setprio around MFMA clusters. XCD-locality: lin&63 = (b,h).
__global__ __launch_bounds__(256, 4) void k_attn(const _Float16* __restrict__ q2,
                                                 const _Float16* __restrict__ k2,
                                                 const _Float16* __restrict__ rel2,
                                                 const _Float16* __restrict__ vb,
                                                 float* __restrict__ out) {
    __shared__ __align__(16) char pool[35840];
    _Float16* kb_s = (_Float16*)pool;            // [64][136] = 17408 B (B-rows [k|q]; phase-0: A-rows)
    _Float16* v_s  = (_Float16*)(pool + 17408);  // [64][72]  =  9216 B
    _Float16* p_s  = (_Float16*)(pool + 26624);  // [64 m][72 n] = 9216 B (wave-private rows)
    int t = threadIdx.x;
    int lane = t & 63, w = t >> 6;
    int lm = lane & 15, lq = lane >> 4;
    int lin = blockIdx.x;
    int mt0 = lin >> 6;          // 0..15 (64 q-rows each)
    int bh_ = lin & 63;
    int h = bh_ & 7, b = bh_ >> 3;
    size_t bh = (size_t)b * 8 + h;
    const _Float16* q2b = q2 + bh * 1024 * 64;
    const _Float16* k2b = k2 + bh * 1024 * 64;
    const _Float16* relb = rel2 + (size_t)h * 1024 * 64;
    const _Float16* vbb = vb + bh * 64 * 1024;
    float* outb = out + bh * 64 * 1024 + mt0 * 64;

    int r = t >> 2, part = t & 3;
    const _Float16* ksrc = ((part < 2) ? (k2b + part * 32) : (q2b + (part - 2) * 32));
    int vc = (t & 3) * 16;
    const _Float16* vsrcb = vbb + (size_t)r * 1024 + vc;
    _Float16* kdst = kb_s + r * 136 + part * 32;
    _Float16* vdst = v_s + r * 72 + vc;

    // prefetch tile 0 into named scalar registers
    uint4 kc0, kc1, kc2, kc3, vv0, vv1;
    {
        const uint4* s_ = (const uint4*)(ksrc + (size_t)r * 64);
        kc0 = s_[0]; kc1 = s_[1]; kc2 = s_[2]; kc3 = s_[3];
        const uint4* v_ = (const uint4*)vsrcb;
        vv0 = v_[0]; vv1 = v_[1];
    }

    // Phase 0: stage A-rows [q | rel] for m = mt0*64 + 0..63
    {
        int n = mt0 * 64 + r;
        const _Float16* src = (part < 2) ? (q2b + (size_t)n * 64 + part * 32)
                                         : (relb + (size_t)n * 64 + (part - 2) * 32);
        ((uint4*)kdst)[0] = ((const uint4*)src)[0];
        ((uint4*)kdst)[1] = ((const uint4*)src)[1];
        ((uint4*)kdst)[2] = ((const uint4*)src)[2];
        ((uint4*)kdst)[3] = ((const uint4*)src)[3];
    }
    __syncthreads();
    half8 ah0[4];
#pragma unroll
    for (int kk = 0; kk < 4; ++kk)
        ah0[kk] = *(half8*)&kb_s[(w * 16 + lm) * 136 + kk * 32 + lq * 8];
    __syncthreads();   // ah0 reads complete before first K ds_write

    f32x4 acco0[4];
#pragma unroll
    for (int i = 0; i < 4; ++i) acco0[i] = {0.f, 0.f, 0.f, 0.f};
    float mrun0 = -3e38f, lrun0 = 0.f;

    for (int kt = 0; kt < 16; ++kt) {
        ((uint4*)kdst)[0] = kc0;
        ((uint4*)kdst)[1] = kc1;
        ((uint4*)kdst)[2] = kc2;
        ((uint4*)kdst)[3] = kc3;
        ((uint4*)vdst)[0] = vv0;
        ((uint4*)vdst)[1] = vv1;
        __syncthreads();
        int nn = ((kt + 1) & 15) * 64;
        const uint4* s_ = (const uint4*)(ksrc + (size_t)(nn + r) * 64);
        uint4 kn0 = s_[0], kn1 = s_[1], kn2 = s_[2], kn3 = s_[3];
        const uint4* v_ = (const uint4*)(vsrcb + nn);
        uint4 vn0 = v_[0], vn1 = v_[1];
        // S^T: s0[ct][reg] -> n = ct*16 + lq*4 + reg, m = w*16 + lm
        f32x4 s0[4];
#pragma unroll
        for (int ct = 0; ct < 4; ++ct) s0[ct] = {0.f, 0.f, 0.f, 0.f};
        __builtin_amdgcn_s_setprio(1);
#pragma unroll
        for (int ct = 0; ct < 4; ++ct) {
            half8 kf[4];
#pragma unroll
            for (int kk = 0; kk < 4; ++kk)
                kf[kk] = *(half8*)&kb_s[(ct * 16 + lm) * 136 + kk * 32 + lq * 8];
#pragma unroll
            for (int kk = 0; kk < 4; ++kk)
                s0[ct] = __builtin_amdgcn_mfma_f32_16x16x32_f16(kf[kk], ah0[kk], s0[ct], 0, 0, 0);
        }
        __builtin_amdgcn_s_setprio(0);
        // softmax (per-lane column m; exp2 domain; defer-max THR=8)
        {
            float mx = -3e38f;
#pragma unroll
            for (int ct = 0; ct < 4; ++ct) {
                float a_ = fmaxf(s0[ct][0], s0[ct][1]);
                float b2 = fmaxf(s0[ct][2], s0[ct][3]);
                mx = fmaxf(mx, fmaxf(a_, b2));
            }
            mx = fmaxf(mx, __shfl_xor(mx, 16));
            mx = fmaxf(mx, __shfl_xor(mx, 32));
            if (__any(mx > mrun0 + 8.f)) {
                float mnew = fmaxf(mrun0, mx);
                float al_ = exp2f(mrun0 - mnew);
                lrun0 *= al_;
#pragma unroll
                for (int dt = 0; dt < 4; ++dt) {
                    acco0[dt][0] *= al_; acco0[dt][1] *= al_;
                    acco0[dt][2] *= al_; acco0[dt][3] *= al_;
                }
                mrun0 = mnew;
            }
            float rs = 0.f;
#pragma unroll
            for (int ct = 0; ct < 4; ++ct) {
                float p0 = exp2f(s0[ct][0] - mrun0);
                float p1 = exp2f(s0[ct][1] - mrun0);
                float p2 = exp2f(s0[ct][2] - mrun0);
                float p3 = exp2f(s0[ct][3] - mrun0);
                rs += (p0 + p1) + (p2 + p3);
                fp16x2 lo = __builtin_amdgcn_cvt_pkrtz(p0, p1);
                fp16x2 hi = __builtin_amdgcn_cvt_pkrtz(p2, p3);
                uint2 pk;
                pk.x = __builtin_bit_cast(unsigned int, lo);
                pk.y = __builtin_bit_cast(unsigned int, hi);
                *(uint2*)&p_s[(w * 16 + lm) * 72 + ct * 16 + lq * 4] = pk;
            }
            rs += __shfl_xor(rs, 16);
            rs += __shfl_xor(rs, 32);
            lrun0 += rs;
        }
        // PV
        half8 p0f[2];
#pragma unroll
        for (int ch = 0; ch < 2; ++ch)
            p0f[ch] = *(half8*)&p_s[(w * 16 + lm) * 72 + ch * 32 + lq * 8];
        __builtin_amdgcn_s_setprio(1);
#pragma unroll
        for (int dt = 0; dt < 4; ++dt) {
            half8 vf0 = *(half8*)&v_s[(dt * 16 + lm) * 72 + lq * 8];
            half8 vf1 = *(half8*)&v_s[(dt * 16 + lm) * 72 + 32 + lq * 8];
            acco0[dt] = __builtin_amdgcn_mfma_f32_16x16x32_f16(vf0, p0f[0], acco0[dt], 0, 0, 0);
            acco0[dt] = __builtin_amdgcn_mfma_f32_16x16x32_f16(vf1, p0f[1], acco0[dt], 0, 0, 0);
        }
        __builtin_amdgcn_s_setprio(0);
        __syncthreads();   // all reads of kb_s/v_s done before next ds_write
        kc0 = kn0; kc1 = kn1; kc2 = kn2; kc3 = kn3;
        vv0 = vn0; vv1 = vn1;
    }
    float li0 = 1.f / lrun0;
#pragma unroll
    for (int dt = 0; dt < 4; ++dt)
#pragma unroll
        for (int reg = 0; reg < 4; ++reg) {
            int d = dt * 16 + lq * 4 + reg;
            outb[(size_t)d * 1024 + w * 16 + lm] = acco0[dt][reg] * li0;
        }
}

extern "C" void kernel_launch(void* const* d_in, const int* in_sizes, int n_in,
                              void* d_out, int out_size, void* d_ws, size_t ws_size,
                              hipStream_t stream) {
    const float* x     = (const float*)d_in[0];
    const float* Wq    = (const float*)d_in[1];
    const float* bq    = (const float*)d_in[2];
    const float* Wk    = (const float*)d_in[3];
    const float* bk    = (const float*)d_in[4];
    const float* Wv    = (const float*)d_in[5];
    const float* bv    = (const float*)d_in[6];
    const float* rel_h = (const float*)d_in[7];
    const float* rel_w = (const float*)d_in[8];
    char* ws = (char*)d_ws;
    _Float16* Wf   = (_Float16*)(ws);               //  1,572,864 B
    float* bias2   = (float*)(ws + 1572864);        //      6,144 B -> 1,579,008
    _Float16* xTf  = (_Float16*)(ws + 1579008);     //  8,388,608 B -> 9,967,616
    _Float16* q2   = (_Float16*)(ws + 9967616);     //  8,388,608 B -> 18,356,224
    _Float16* k2   = (_Float16*)(ws + 18356224);    //  8,388,608 B -> 26,744,832
    _Float16* vb   = (_Float16*)(ws + 26744832);    //  8,388,608 B -> 35,133,440
    _Float16* rel2 = (_Float16*)(ws + 35133440);    //  1,048,576 B -> 36,182,016
    float* out = (float*)d_out;

    hipLaunchKernelGGL(k_prep_all, dim3(1664),     dim3(256), 0, stream,
                       Wq, Wk, Wv, bq, bk, bv, x, rel_h, rel_w, Wf, bias2, xTf, rel2);
    hipLaunchKernelGGL(k_proj,     dim3(8, 12, 8), dim3(256), 0, stream, Wf, xTf, bias2, q2, k2, vb);
    hipLaunchKernelGGL(k_attn,     dim3(1024),     dim3(256), 0, stream, q2, k2, rel2, vb, out);
}

// Round 3
// 152.547 us; speedup vs baseline: 1.0136x; 1.0136x over previous
//
#include <hip/hip_runtime.h>

typedef _Float16 half8 __attribute__((ext_vector_type(8)));
typedef _Float16 half4 __attribute__((ext_vector_type(4)));
typedef __fp16 fp16x2 __attribute__((ext_vector_type(2)));
typedef float f32x4 __attribute__((ext_vector_type(4)));

__device__ __forceinline__ void glds16(const void* g, void* l) {
    __builtin_amdgcn_global_load_lds(
        (const __attribute__((address_space(1))) unsigned int*)g,
        (__attribute__((address_space(3))) unsigned int*)l, 16, 0, 0);
}

// ---------------------------------------------------------------------------
// Sizes: B=8, C=512, H=8, D=64, N=1024. Projection: M=1536 (q|k|v), K=512 fp16.
// ---------------------------------------------------------------------------

// Merged prep: [0,384) pack W->fp16; [384,1408) transpose x->fp16; [1408,1664) rel.
__global__ void k_prep_all(const float* __restrict__ Wq, const float* __restrict__ Wk,
                           const float* __restrict__ Wv, const float* __restrict__ bq,
                           const float* __restrict__ bk, const float* __restrict__ bv,
                           const float* __restrict__ x, const float* __restrict__ rel_h,
                           const float* __restrict__ rel_w, _Float16* __restrict__ Wf,
                           float* __restrict__ bias2, _Float16* __restrict__ xTf,
                           _Float16* __restrict__ rel2) {
    __shared__ float xs[64][65];
    int bid = blockIdx.x;
    if (bid < 384) {
        int t = bid * 256 + threadIdx.x;          // 98304 threads
        int m = t >> 6;
        int c8 = (t & 63) << 3;
        const float* src = (m < 512) ? (Wq + m * 512)
                         : (m < 1024 ? (Wk + (m - 512) * 512) : (Wv + (m - 1024) * 512));
        float4 v0 = *(const float4*)(src + c8);
        float4 v1 = *(const float4*)(src + c8 + 4);
        half8 o;
        o[0] = (_Float16)v0.x; o[1] = (_Float16)v0.y; o[2] = (_Float16)v0.z; o[3] = (_Float16)v0.w;
        o[4] = (_Float16)v1.x; o[5] = (_Float16)v1.y; o[6] = (_Float16)v1.z; o[7] = (_Float16)v1.w;
        *(half8*)(Wf + (size_t)m * 512 + c8) = o;
        if (t < 1536)
            bias2[t] = (t < 512) ? bq[t] : (t < 1024 ? bk[t - 512] : bv[t - 1024]);
    } else if (bid < 1408) {
        int i = bid - 384;
        int nt = (i & 15) << 6, ct = ((i >> 4) & 7) << 6, b = i >> 7;
        int t = threadIdx.x;
        const float* xb = x + ((size_t)b * 512 + ct) * 1024 + nt;
#pragma unroll
        for (int p = 0; p < 4; ++p) {
            int c = p * 16 + (t >> 4), n4 = (t & 15) * 4;
            float4 v = *(const float4*)(xb + (size_t)c * 1024 + n4);
            xs[c][n4] = v.x; xs[c][n4 + 1] = v.y; xs[c][n4 + 2] = v.z; xs[c][n4 + 3] = v.w;
        }
        __syncthreads();
        int nl = t >> 2, part = t & 3;
        _Float16* rowp = xTf + ((size_t)b * 1024 + nt + nl) * 512;
#pragma unroll
        for (int g = 0; g < 2; ++g) {
            half8 o;
#pragma unroll
            for (int j = 0; j < 8; ++j)
                o[j] = (_Float16)xs[part * 16 + g * 8 + j][nl];
            *(half8*)(rowp + ct + part * 16 + g * 8) = o;
        }
    } else {
        int tid = (bid - 1408) * 256 + threadIdx.x;   // 65536
        int h = tid >> 13;
        int rem = tid & 8191;
        int n = rem >> 3;
        int g = rem & 7;
        int hh = n & 31, ww = n >> 5;
        half8 o;
#pragma unroll
        for (int j = 0; j < 8; ++j) {
            int d = g * 8 + j;
            o[j] = (_Float16)(rel_h[(h * 64 + d) * 32 + hh] + rel_w[(h * 64 + d) * 32 + ww]);
        }
        *(half8*)(rel2 + ((size_t)h * 1024 + n) * 64 + g * 8) = o;
    }
}

// fp16 GEMM K=512, BK=64; glds16 + XOR-swizzled LDS. Epilogue writes q2 (scaled
// by log2e for the exp2 softmax), k2 ([bh][n][d]) and vb ([bh][d][n]).
__global__ __launch_bounds__(256, 3) void k_proj(const _Float16* __restrict__ Wf,
                                                 const _Float16* __restrict__ xTf,
                                                 const float* __restrict__ bias2,
                                                 _Float16* __restrict__ q2,
                                                 _Float16* __restrict__ k2,
                                                 _Float16* __restrict__ vb) {
    __shared__ __align__(16) _Float16 As[8192];   // [2 kh][128 rows][32 halfs], swizzled
    __shared__ __align__(16) _Float16 Bs[8192];
    int t = threadIdx.x;
    int lane = t & 63, w = t >> 6;
    int lm = lane & 15, lq = lane >> 4;
    int wr = (w >> 1) * 64, wc = (w & 1) * 64;
    int mb = blockIdx.y * 128, nb = blockIdx.x * 128, b = blockIdx.z;
    int rl = lane >> 2;                                   // row within 16-row group
    int csw = ((lane & 3) ^ ((lane >> 3) & 3)) * 8;       // swizzled col (halfs)
    const _Float16* Ag0 = Wf + (size_t)(mb + w * 32 + rl) * 512 + csw;
    const _Float16* Ag1 = Ag0 + 16 * 512;
    const _Float16* Bg0 = xTf + ((size_t)b * 1024 + nb + w * 32 + rl) * 512 + csw;
    const _Float16* Bg1 = Bg0 + 16 * 512;
    f32x4 acc[4][4];
#pragma unroll
    for (int i = 0; i < 4; ++i)
#pragma unroll
        for (int j = 0; j < 4; ++j) acc[i][j] = {0.f, 0.f, 0.f, 0.f};
    int fsw = (lq ^ ((lm >> 1) & 3)) * 8;                 // fragment-read swizzle
    for (int k0 = 0; k0 < 512; k0 += 64) {
#pragma unroll
        for (int kh = 0; kh < 2; ++kh) {
            int ko = k0 + kh * 32;
            glds16(Ag0 + ko, &As[kh * 4096 + (w * 32) * 32]);
            glds16(Ag1 + ko, &As[kh * 4096 + (w * 32 + 16) * 32]);
            glds16(Bg0 + ko, &Bs[kh * 4096 + (w * 32) * 32]);
            glds16(Bg1 + ko, &Bs[kh * 4096 + (w * 32 + 16) * 32]);
        }
        __syncthreads();
#pragma unroll
        for (int kh = 0; kh < 2; ++kh) {
            half8 af[4], bfr[4];
#pragma unroll
            for (int mt = 0; mt < 4; ++mt)
                af[mt] = *(half8*)&As[kh * 4096 + (wr + mt * 16 + lm) * 32 + fsw];
#pragma unroll
            for (int nt = 0; nt < 4; ++nt)
                bfr[nt] = *(half8*)&Bs[kh * 4096 + (wc + nt * 16 + lm) * 32 + fsw];
#pragma unroll
            for (int mt = 0; mt < 4; ++mt)
#pragma unroll
                for (int nt = 0; nt < 4; ++nt)
                    acc[mt][nt] = __builtin_amdgcn_mfma_f32_16x16x32_f16(af[mt], bfr[nt], acc[mt][nt], 0, 0, 0);
        }
        __syncthreads();
    }
    // Epilogue: section 0=q, 1=k, 2=v; head-aligned since (mb+wr)%64==0.
    // q scaled by log2e so k_attn can use native exp2 (S gets the factor exactly:
    // q is the A-half of q·k and the B-half of rel·q).
    int sect = mb >> 9;
    int hloc = ((mb & 511) + wr) >> 6;
    size_t bh = (size_t)b * 8 + hloc;
    if (sect < 2) {
        float sc = (sect == 0) ? 1.44269504089f : 1.0f;
        _Float16* dst = (sect == 0 ? q2 : k2) + bh * 1024 * 64;
#pragma unroll
        for (int mt = 0; mt < 4; ++mt) {
            int d0 = mt * 16 + lq * 4;
            float bi0 = bias2[mb + wr + d0];
            float bi1 = bias2[mb + wr + d0 + 1];
            float bi2 = bias2[mb + wr + d0 + 2];
            float bi3 = bias2[mb + wr + d0 + 3];
#pragma unroll
            for (int nt = 0; nt < 4; ++nt) {
                int n = nb + wc + nt * 16 + lm;
                half4 o;
                o[0] = (_Float16)((acc[mt][nt][0] + bi0) * sc);
                o[1] = (_Float16)((acc[mt][nt][1] + bi1) * sc);
                o[2] = (_Float16)((acc[mt][nt][2] + bi2) * sc);
                o[3] = (_Float16)((acc[mt][nt][3] + bi3) * sc);
                *(half4*)(dst + (size_t)n * 64 + d0) = o;
            }
        }
    } else {
        _Float16* dst = vb + bh * 64 * 1024;
#pragma unroll
        for (int mt = 0; mt < 4; ++mt)
#pragma unroll
            for (int reg = 0; reg < 4; ++reg) {
                int d = mt * 16 + lq * 4 + reg;
                float bi = bias2[mb + wr + d];
#pragma unroll
                for (int nt = 0; nt < 4; ++nt) {
                    int n = nb + wc + nt * 16 + lm;
                    dst[(size_t)d * 1024 + n] = (_Float16)(acc[mt][nt][reg] + bi);
                }
            }
    }
}

// Flash attention, fp16, S^T orientation, Mtile=128 (2 q-tiles per block share
// K/V staging and kf fragments — lowest LDS traffic per output). Power-of-two
// row strides + XOR swizzle (byte ^= (row&7)<<4) on ALL LDS tiles: old strides
// (68/36 dw == 4 mod 32) put 16-lane row-sliced b128 reads on 8 banks (8-way).
// exp2 softmax (q pre-scaled), defer-max THR=8, pkrtz pack, setprio.
__global__ __launch_bounds__(256, 3) void k_attn(const _Float16* __restrict__ q2,
                                                 const _Float16* __restrict__ k2,
                                                 const _Float16* __restrict__ rel2,
                                                 const _Float16* __restrict__ vb,
                                                 float* __restrict__ out) {
    __shared__ __align__(16) char pool[40960];
    char* kb_s = pool;            // [64 rows][256 B]  ([k|q] halfs, swizzled)
    char* v_s  = pool + 16384;    // [64 rows][128 B]  (V: row=d, col=n, swizzled)
    char* p_s  = pool + 24576;    // [128 rows][128 B] (P, wave-private rows, swizzled)
    int t = threadIdx.x;
    int lane = t & 63, w = t >> 6;
    int lm = lane & 15, lq = lane >> 4;
    int lin = blockIdx.x;
    int mt0 = lin >> 6;          // 0..7 (128 q-rows each)
    int bh_ = lin & 63;
    int h = bh_ & 7, b = bh_ >> 3;
    size_t bh = (size_t)b * 8 + h;
    const _Float16* q2b = q2 + bh * 1024 * 64;
    const _Float16* k2b = k2 + bh * 1024 * 64;
    const _Float16* relb = rel2 + (size_t)h * 1024 * 64;
    const _Float16* vbb = vb + bh * 64 * 1024;
    float* outb = out + bh * 64 * 1024 + mt0 * 128;

    int r = t >> 2, part = t & 3;
    int wsw = (r & 7) << 4;                     // write-side swizzle
    int rsw = (lm & 7) << 4;                    // read-side swizzle (all frag rows are X*16+lm)
    const _Float16* ksrc = ((part < 2) ? (k2b + part * 32) : (q2b + (part - 2) * 32));
    const _Float16* vsrcb = vbb + (size_t)r * 1024 + part * 16;
    char* kdst = kb_s + r * 256;
    char* vdst = v_s + r * 128;

    // prefetch tile 0 into named scalar registers
    uint4 kc0, kc1, kc2, kc3, vv0, vv1;
    {
        const uint4* s_ = (const uint4*)(ksrc + (size_t)r * 64);
        kc0 = s_[0]; kc1 = s_[1]; kc2 = s_[2]; kc3 = s_[3];
        const uint4* v_ = (const uint4*)vsrcb;
        vv0 = v_[0]; vv1 = v_[1];
    }

    // Phase 0 round A: stage A-rows [q | rel] for m = mt0*128 + 0..63
    {
        int n = mt0 * 128 + r;
        const _Float16* src = (part < 2) ? (q2b + (size_t)n * 64 + part * 32)
                                         : (relb + (size_t)n * 64 + (part - 2) * 32);
        *(uint4*)(kdst + ((part * 64 +  0) ^ wsw)) = ((const uint4*)src)[0];
        *(uint4*)(kdst + ((part * 64 + 16) ^ wsw)) = ((const uint4*)src)[1];
        *(uint4*)(kdst + ((part * 64 + 32) ^ wsw)) = ((const uint4*)src)[2];
        *(uint4*)(kdst + ((part * 64 + 48) ^ wsw)) = ((const uint4*)src)[3];
    }
    __syncthreads();
    half8 ah0[4], ah1[4];
#pragma unroll
    for (int kk = 0; kk < 4; ++kk)
        ah0[kk] = *(half8*)(kb_s + (w * 16 + lm) * 256 + ((kk * 64 + lq * 16) ^ rsw));
    __syncthreads();
    // Phase 0 round B: rows m = mt0*128 + 64..127
    {
        int n = mt0 * 128 + 64 + r;
        const _Float16* src = (part < 2) ? (q2b + (size_t)n * 64 + part * 32)
                                         : (relb + (size_t)n * 64 + (part - 2) * 32);
        *(uint4*)(kdst + ((part * 64 +  0) ^ wsw)) = ((const uint4*)src)[0];
        *(uint4*)(kdst + ((part * 64 + 16) ^ wsw)) = ((const uint4*)src)[1];
        *(uint4*)(kdst + ((part * 64 + 32) ^ wsw)) = ((const uint4*)src)[2];
        *(uint4*)(kdst + ((part * 64 + 48) ^ wsw)) = ((const uint4*)src)[3];
    }
    __syncthreads();
#pragma unroll
    for (int kk = 0; kk < 4; ++kk)
        ah1[kk] = *(half8*)(kb_s + (w * 16 + lm) * 256 + ((kk * 64 + lq * 16) ^ rsw));
    __syncthreads();   // ah1 reads complete before first K ds_write

    f32x4 acco0[4], acco1[4];
#pragma unroll
    for (int i = 0; i < 4; ++i) { acco0[i] = {0.f, 0.f, 0.f, 0.f}; acco1[i] = {0.f, 0.f, 0.f, 0.f}; }
    float mrun0 = -3e38f, lrun0 = 0.f, mrun1 = -3e38f, lrun1 = 0.f;

    for (int kt = 0; kt < 16; ++kt) {
        *(uint4*)(kdst + ((part * 64 +  0) ^ wsw)) = kc0;
        *(uint4*)(kdst + ((part * 64 + 16) ^ wsw)) = kc1;
        *(uint4*)(kdst + ((part * 64 + 32) ^ wsw)) = kc2;
        *(uint4*)(kdst + ((part * 64 + 48) ^ wsw)) = kc3;
        *(uint4*)(vdst + ((part * 32 +  0) ^ wsw)) = vv0;
        *(uint4*)(vdst + ((part * 32 + 16) ^ wsw)) = vv1;
        __syncthreads();
        int nn = ((kt + 1) & 15) * 64;
        const uint4* s_ = (const uint4*)(ksrc + (size_t)(nn + r) * 64);
        uint4 kn0 = s_[0], kn1 = s_[1], kn2 = s_[2], kn3 = s_[3];
        const uint4* v_ = (const uint4*)(vsrcb + nn);
        uint4 vn0 = v_[0], vn1 = v_[1];
        // S^T: s0/s1[ct][reg] -> n = ct*16 + lq*4 + reg, m = w*16 + lm (+64 for s1)
        f32x4 s0[4], s1[4];
#pragma unroll
        for (int ct = 0; ct < 4; ++ct) { s0[ct] = {0.f, 0.f, 0.f, 0.f}; s1[ct] = {0.f, 0.f, 0.f, 0.f}; }
        __builtin_amdgcn_s_setprio(1);
#pragma unroll
        for (int ct = 0; ct < 4; ++ct) {
            half8 kf[4];
#pragma unroll
            for (int kk = 0; kk < 4; ++kk)
                kf[kk] = *(half8*)(kb_s + (ct * 16 + lm) * 256 + ((kk * 64 + lq * 16) ^ rsw));
#pragma unroll
            for (int kk = 0; kk < 4; ++kk) {
                s0[ct] = __builtin_amdgcn_mfma_f32_16x16x32_f16(kf[kk], ah0[kk], s0[ct], 0, 0, 0);
                s1[ct] = __builtin_amdgcn_mfma_f32_16x16x32_f16(kf[kk], ah1[kk], s1[ct], 0, 0, 0);
            }
        }
        __builtin_amdgcn_s_setprio(0);
        // softmax tile 0 (per-lane column m; exp2 domain; defer-max THR=8)
        {
            float mx = -3e38f;
#pragma unroll
            for (int ct = 0; ct < 4; ++ct) {
                float a_ = fmaxf(s0[ct][0], s0[ct][1]);
                float b2 = fmaxf(s0[ct][2], s0[ct][3]);
                mx = fmaxf(mx, fmaxf(a_, b2));
            }
            mx = fmaxf(mx, __shfl_xor(mx, 16));
            mx = fmaxf(mx, __shfl_xor(mx, 32));
            if (__any(mx > mrun0 + 8.f)) {
                float mnew = fmaxf(mrun0, mx);
                float al_ = exp2f(mrun0 - mnew);
                lrun0 *= al_;
#pragma unroll
                for (int dt = 0; dt < 4; ++dt) {
                    acco0[dt][0] *= al_; acco0[dt][1] *= al_;
                    acco0[dt][2] *= al_; acco0[dt][3] *= al_;
                }
                mrun0 = mnew;
            }
            float rs = 0.f;
            char* prow = p_s + (w * 16 + lm) * 128;
#pragma unroll
            for (int ct = 0; ct < 4; ++ct) {
                float p0 = exp2f(s0[ct][0] - mrun0);
                float p1 = exp2f(s0[ct][1] - mrun0);
                float p2 = exp2f(s0[ct][2] - mrun0);
                float p3 = exp2f(s0[ct][3] - mrun0);
                rs += (p0 + p1) + (p2 + p3);
                fp16x2 lo = __builtin_amdgcn_cvt_pkrtz(p0, p1);
                fp16x2 hi = __builtin_amdgcn_cvt_pkrtz(p2, p3);
                uint2 pk;
                pk.x = __builtin_bit_cast(unsigned int, lo);
                pk.y = __builtin_bit_cast(unsigned int, hi);
                *(uint2*)(prow + ((ct * 32 + lq * 8) ^ rsw)) = pk;
            }
            rs += __shfl_xor(rs, 16);
            rs += __shfl_xor(rs, 32);
            lrun0 += rs;
        }
        // softmax tile 1
        {
            float mx = -3e38f;
#pragma unroll
            for (int ct = 0; ct < 4; ++ct) {
                float a_ = fmaxf(s1[ct][0], s1[ct][1]);
                float b2 = fmaxf(s1[ct][2], s1[ct][3]);
                mx = fmaxf(mx, fmaxf(a_, b2));
            }
            mx = fmaxf(mx, __shfl_xor(mx, 16));
            mx = fmaxf(mx, __shfl_xor(mx, 32));
            if (__any(mx > mrun1 + 8.f)) {
                float mnew = fmaxf(mrun1, mx);
                float al_ = exp2f(mrun1 - mnew);
                lrun1 *= al_;
#pragma unroll
                for (int dt = 0; dt < 4; ++dt) {
                    acco1[dt][0] *= al_; acco1[dt][1] *= al_;
                    acco1[dt][2] *= al_; acco1[dt][3] *= al_;
                }
                mrun1 = mnew;
            }
            float rs = 0.f;
            char* prow = p_s + (64 + w * 16 + lm) * 128;
#pragma unroll
            for (int ct = 0; ct < 4; ++ct) {
                float p0 = exp2f(s1[ct][0] - mrun1);
                float p1 = exp2f(s1[ct][1] - mrun1);
                float p2 = exp2f(s1[ct][2] - mrun1);
                float p3 = exp2f(s1[ct][3] - mrun1);
                rs += (p0 + p1) + (p2 + p3);
                fp16x2 lo = __builtin_amdgcn_cvt_pkrtz(p0, p1);
                fp16x2 hi = __builtin_amdgcn_cvt_pkrtz(p2, p3);
                uint2 pk;
                pk.x = __builtin_bit_cast(unsigned int, lo);
                pk.y = __builtin_bit_cast(unsigned int, hi);
                *(uint2*)(prow + ((ct * 32 + lq * 8) ^ rsw)) = pk;
            }
            rs += __shfl_xor(rs, 16);
            rs += __shfl_xor(rs, 32);
            lrun1 += rs;
        }
        // PV for both tiles; v fragments shared
        half8 p0f[2], p1f[2];
#pragma unroll
        for (int ch = 0; ch < 2; ++ch) {
            p0f[ch] = *(half8*)(p_s + (w * 16 + lm) * 128 + ((ch * 64 + lq * 16) ^ rsw));
            p1f[ch] = *(half8*)(p_s + (64 + w * 16 + lm) * 128 + ((ch * 64 + lq * 16) ^ rsw));
        }
        __builtin_amdgcn_s_setprio(1);
#pragma unroll
        for (int dt = 0; dt < 4; ++dt) {
            half8 vf0 = *(half8*)(v_s + (dt * 16 + lm) * 128 + ((lq * 16) ^ rsw));
            half8 vf1 = *(half8*)(v_s + (dt * 16 + lm) * 128 + ((64 + lq * 16) ^ rsw));
            acco0[dt] = __builtin_amdgcn_mfma_f32_16x16x32_f16(vf0, p0f[0], acco0[dt], 0, 0, 0);
            acco0[dt] = __builtin_amdgcn_mfma_f32_16x16x32_f16(vf1, p0f[1], acco0[dt], 0, 0, 0);
            acco1[dt] = __builtin_amdgcn_mfma_f32_16x16x32_f16(vf0, p1f[0], acco1[dt], 0, 0, 0);
            acco1[dt] = __builtin_amdgcn_mfma_f32_16x16x32_f16(vf1, p1f[1], acco1[dt], 0, 0, 0);
        }
        __builtin_amdgcn_s_setprio(0);
        __syncthreads();   // all reads of kb_s/v_s done before next ds_write
        kc0 = kn0; kc1 = kn1; kc2 = kn2; kc3 = kn3;
        vv0 = vn0; vv1 = vn1;
    }
    float li0 = 1.f / lrun0, li1 = 1.f / lrun1;
#pragma unroll
    for (int dt = 0; dt < 4; ++dt)
#pragma unroll
        for (int reg = 0; reg < 4; ++reg) {
            int d = dt * 16 + lq * 4 + reg;
            outb[(size_t)d * 1024 + w * 16 + lm] = acco0[dt][reg] * li0;
            outb[(size_t)d * 1024 + 64 + w * 16 + lm] = acco1[dt][reg] * li1;
        }
}

extern "C" void kernel_launch(void* const* d_in, const int* in_sizes, int n_in,
                              void* d_out, int out_size, void* d_ws, size_t ws_size,
                              hipStream_t stream) {
    const float* x     = (const float*)d_in[0];
    const float* Wq    = (const float*)d_in[1];
    const float* bq    = (const float*)d_in[2];
    const float* Wk    = (const float*)d_in[3];
    const float* bk    = (const float*)d_in[4];
    const float* Wv    = (const float*)d_in[5];
    const float* bv    = (const float*)d_in[6];
    const float* rel_h = (const float*)d_in[7];
    const float* rel_w = (const float*)d_in[8];
    char* ws = (char*)d_ws;
    _Float16* Wf   = (_Float16*)(ws);               //  1,572,864 B
    float* bias2   = (float*)(ws + 1572864);        //      6,144 B -> 1,579,008
    _Float16* xTf  = (_Float16*)(ws + 1579008);     //  8,388,608 B -> 9,967,616
    _Float16* q2   = (_Float16*)(ws + 9967616);     //  8,388,608 B -> 18,356,224
    _Float16* k2   = (_Float16*)(ws + 18356224);    //  8,388,608 B -> 26,744,832
    _Float16* vb   = (_Float16*)(ws + 26744832);    //  8,388,608 B -> 35,133,440
    _Float16* rel2 = (_Float16*)(ws + 35133440);    //  1,048,576 B -> 36,182,016
    float* out = (float*)d_out;

    hipLaunchKernelGGL(k_prep_all, dim3(1664),     dim3(256), 0, stream,
                       Wq, Wk, Wv, bq, bk, bv, x, rel_h, rel_w, Wf, bias2, xTf, rel2);
    hipLaunchKernelGGL(k_proj,     dim3(8, 12, 8), dim3(256), 0, stream, Wf, xTf, bias2, q2, k2, vb);
    hipLaunchKernelGGL(k_attn,     dim3(512),      dim3(256), 0, stream, q2, k2, rel2, vb, out);
}